// Round 13
// baseline (133.997 us; speedup 1.0000x reference)
//
#include <hip/hip_runtime.h>
#include <hip/hip_bf16.h>
#include <stdint.h>

#define BB 8
#define SS 1024
#define DD 768
#define HH 12
#define DHH 64
#define BS (BB*SS)        // 8192
#define NQKV (3*HH*DHH)   // 2304

typedef __attribute__((ext_vector_type(8))) short bf16x8;
typedef __attribute__((ext_vector_type(4))) float f32x4;
typedef __attribute__((ext_vector_type(4))) unsigned int u32x4;

typedef const __attribute__((address_space(1))) unsigned int gu32;
typedef __attribute__((address_space(3))) unsigned int lu32;

static __device__ __forceinline__ unsigned short f2bf(float f) {
    union { float f; unsigned int u; } v; v.f = f;
    unsigned int u = v.u;
    unsigned int r = (u + 0x7fffu + ((u >> 16) & 1u)) >> 16;
    return (unsigned short)r;
}

static __device__ __forceinline__ unsigned int cvt_pk_bf16(float lo, float hi) {
    unsigned int r;
    asm("v_cvt_pk_bf16_f32 %0, %1, %2" : "=v"(r) : "v"(lo), "v"(hi));
    return r;
}

// ---------------- prep kernels ----------------

__global__ void k_f32_to_bf16(const float* __restrict__ in, unsigned short* __restrict__ out, int n) {
    int i = (blockIdx.x * 256 + threadIdx.x) * 4;
    if (i + 3 < n) {
        float4 v = *reinterpret_cast<const float4*>(in + i);
        ushort4 o;
        o.x = f2bf(v.x); o.y = f2bf(v.y); o.z = f2bf(v.z); o.w = f2bf(v.w);
        *reinterpret_cast<ushort4*>(out + i) = o;
    } else {
        for (; i < n; ++i) out[i] = f2bf(in[i]);
    }
}

// wt[c][d] (c = mat*768 + h*64 + e) = W_mat[h][d][e], via LDS 64x64 tile transpose.
__global__ void k_transpose_wqkv(const float* __restrict__ wq, const float* __restrict__ wk,
                                 const float* __restrict__ wv, unsigned short* __restrict__ wt) {
    __shared__ float tl[64][65];
    int rt = blockIdx.x;       // d tile
    int z = blockIdx.y;        // 0..35
    int mat = z / 12, h = z - mat * 12;
    const float* src = ((mat == 0) ? wq : (mat == 1) ? wk : wv) + (size_t)h * 768 * 64; // [768][64]
    int d0 = rt * 64;
    int t = threadIdx.x;
    int row = t >> 4, c4 = (t & 15) * 4;
    #pragma unroll
    for (int p = 0; p < 4; ++p) {
        int d = p * 16 + row;
        float4 v = *reinterpret_cast<const float4*>(&src[(size_t)(d0 + d) * 64 + c4]);
        tl[d][c4 + 0] = v.x; tl[d][c4 + 1] = v.y; tl[d][c4 + 2] = v.z; tl[d][c4 + 3] = v.w;
    }
    __syncthreads();
    unsigned short* dstb = wt + ((size_t)(mat * 768 + h * 64)) * 768;
    #pragma unroll
    for (int p = 0; p < 4; ++p) {
        int e = p * 16 + row;
        ushort4 o;
        o.x = f2bf(tl[c4 + 0][e]); o.y = f2bf(tl[c4 + 1][e]);
        o.z = f2bf(tl[c4 + 2][e]); o.w = f2bf(tl[c4 + 3][e]);
        *reinterpret_cast<ushort4*>(&dstb[(size_t)e * 768 + d0 + c4]) = o;
    }
}

// wot[d][he] = wo[he][d], 64x64 LDS tiles.
__global__ void k_transpose_wo(const float* __restrict__ wo, unsigned short* __restrict__ wot) {
    __shared__ float tl[64][65];
    int r0 = blockIdx.x * 64;   // he tile
    int c0 = blockIdx.y * 64;   // d tile
    int t = threadIdx.x;
    int row = t >> 4, c4 = (t & 15) * 4;
    #pragma unroll
    for (int p = 0; p < 4; ++p) {
        int r = p * 16 + row;
        float4 v = *reinterpret_cast<const float4*>(&wo[(size_t)(r0 + r) * 768 + c0 + c4]);
        tl[r][c4 + 0] = v.x; tl[r][c4 + 1] = v.y; tl[r][c4 + 2] = v.z; tl[r][c4 + 3] = v.w;
    }
    __syncthreads();
    #pragma unroll
    for (int p = 0; p < 4; ++p) {
        int c = p * 16 + row;
        ushort4 o;
        o.x = f2bf(tl[c4 + 0][c]); o.y = f2bf(tl[c4 + 1][c]);
        o.z = f2bf(tl[c4 + 2][c]); o.w = f2bf(tl[c4 + 3][c]);
        *reinterpret_cast<ushort4*>(&wot[(size_t)(c0 + c) * 768 + r0 + c4]) = o;
    }
}

// ---------------- QKV projection GEMM (m97 structure): C[8192,2304] = xb * wt^T ----------------
// R4-exact K-loop (frozen). Epilogue: V written directly transposed
// (vtb[bh][e][s], ushort4 per lane) — k_transpose_v eliminated.

__launch_bounds__(256)
__global__ void k_gemm_qkv(const unsigned short* __restrict__ xb,
                           const unsigned short* __restrict__ wt,
                           const float* __restrict__ bq, const float* __restrict__ bk,
                           const float* __restrict__ bv,
                           unsigned short* __restrict__ qb,
                           unsigned short* __restrict__ kb,
                           unsigned short* __restrict__ vtb) {
    __shared__ unsigned short As[128 * 32];
    __shared__ unsigned short Bs[128 * 32];
    int r0 = blockIdx.x * 128;
    int c0 = blockIdx.y * 128;
    int t = threadIdx.x;
    int w = t >> 6, l = t & 63;
    int lr = l & 15, lg = l >> 4;
    int wr = w >> 1, wc = w & 1;
    int srow = l >> 2, sko = (l & 3) * 8;

    f32x4 acc[4][4] = {};
    for (int k0 = 0; k0 < DD; k0 += 32) {
        __syncthreads();
        #pragma unroll
        for (int c = 0; c < 2; ++c) {
            int seg = w * 2 + c;
            int row = seg * 16 + srow;
            __builtin_amdgcn_global_load_lds(
                (gu32*)(xb + (size_t)(r0 + row) * DD + k0 + sko),
                (lu32*)&As[seg * 512], 16, 0, 0);
            __builtin_amdgcn_global_load_lds(
                (gu32*)(wt + (size_t)(c0 + row) * DD + k0 + sko),
                (lu32*)&Bs[seg * 512], 16, 0, 0);
        }
        __syncthreads();
        bf16x8 af[4], bfr[4];
        #pragma unroll
        for (int m = 0; m < 4; ++m)
            af[m] = *reinterpret_cast<const bf16x8*>(&As[(wr * 64 + m * 16 + lr) * 32 + lg * 8]);
        #pragma unroll
        for (int n = 0; n < 4; ++n)
            bfr[n] = *reinterpret_cast<const bf16x8*>(&Bs[(wc * 64 + n * 16 + lr) * 32 + lg * 8]);
        #pragma unroll
        for (int m = 0; m < 4; ++m)
            #pragma unroll
            for (int n = 0; n < 4; ++n)
                acc[m][n] = __builtin_amdgcn_mfma_f32_16x16x32_bf16(af[m], bfr[n], acc[m][n], 0, 0, 0);
    }
    #pragma unroll
    for (int n = 0; n < 4; ++n) {
        int c = c0 + wc * 64 + n * 16 + lr;
        int mat = c / 768;
        int within = c - mat * 768;
        int h = within >> 6, e = within & 63;
        const float* bptr = (mat == 0) ? bq : (mat == 1) ? bk : bv;
        float bias = bptr[within];
        #pragma unroll
        for (int m = 0; m < 4; ++m) {
            int r = r0 + wr * 64 + m * 16 + lg * 4;
            int b_ = r >> 10, s_ = r & 1023;
            if (mat == 2) {
                ushort4 o;
                o.x = f2bf(acc[m][n][0] + bias);
                o.y = f2bf(acc[m][n][1] + bias);
                o.z = f2bf(acc[m][n][2] + bias);
                o.w = f2bf(acc[m][n][3] + bias);
                *reinterpret_cast<ushort4*>(&vtb[((size_t)(b_ * HH + h) * DHH + e) * SS + s_]) = o;
            } else {
                unsigned short* dst = (mat == 0) ? qb : kb;
                #pragma unroll
                for (int i = 0; i < 4; ++i)
                    dst[(((size_t)(b_ * HH + h)) * SS + s_ + i) * DHH + e] = f2bf(acc[m][n][i] + bias);
            }
        }
    }
}

// ---------------- flash attention: 8-wave 128-row q-blocks ----------------
// R4-proven pipeline (dbuf K AND V, STAGE(next) before compute, ONE
// __syncthreads per iter) with 128 q-rows/block: staging per q-row halves,
// barrier events halve, 24 waves/CU (3 blocks x 8 waves, LDS 49.4 KB).
// Mask: k-tiles kt >= 2*qi apply elementwise kabs>qabs; fully-masked tiles
// for low waves give pm=-3e38 -> defer-max skips rescale, P underflows to 0.

#define PW 34   // u32 row stride for P tile

__launch_bounds__(512, 6)
__global__ void k_attn(const unsigned short* __restrict__ qb,
                       const unsigned short* __restrict__ kb,
                       const unsigned short* __restrict__ vtb,
                       unsigned short* __restrict__ zb) {
    __shared__ unsigned short Ks[2][64 * 64];
    __shared__ unsigned short Vs[2][64 * 64];
    __shared__ unsigned int Pl[8][16 * PW];
    int id = blockIdx.x;           // 0..767
    int xcd = id & 7;              // round-robin dispatch -> XCD
    int j = id >> 3;               // 0..95 within this XCD
    int bh = xcd * 12 + (j % 12);  // this XCD's 12 heads
    int qi = 7 - (j / 12);         // 0..7, heavy-first within XCD
    int q0 = qi * 128;
    int nkt = 2 * qi + 2;

    int t = threadIdx.x, w = t >> 6, l = t & 63;
    int lr = l & 15, lg = l >> 4;
    const unsigned short* Qh = qb + (size_t)bh * SS * DHH;
    const unsigned short* Kh = kb + (size_t)bh * SS * DHH;
    const unsigned short* Vt = vtb + (size_t)bh * DHH * SS;
    int b_ = bh / HH, h = bh - b_ * HH;
    unsigned int* Pw = &Pl[w][0];

    int sr8 = l >> 3;
    int sc = ((l & 7) ^ sr8) * 8;
    int srow = w * 8 + sr8;        // wave w stages rows [w*8, w*8+8)

    auto STAGE = [&](int buf, int kbase) {
        __builtin_amdgcn_global_load_lds(
            (gu32*)(Kh + (size_t)(kbase + srow) * DHH + sc),
            (lu32*)&Ks[buf][w * 512], 16, 0, 0);
        __builtin_amdgcn_global_load_lds(
            (gu32*)(Vt + (size_t)srow * SS + kbase + sc),
            (lu32*)&Vs[buf][w * 512], 16, 0, 0);
    };

    int qabs = q0 + w * 16 + lr;
    STAGE(0, 0);
    bf16x8 qf[2];
    qf[0] = *reinterpret_cast<const bf16x8*>(Qh + (size_t)qabs * DHH + lg * 8);
    qf[1] = *reinterpret_cast<const bf16x8*>(Qh + (size_t)qabs * DHH + 32 + lg * 8);

    float m_r = -3.0e38f, l_r = 0.f;
    f32x4 zacc[4] = {};
    __syncthreads();   // buf0 ready

    for (int kt = 0; kt < nkt; ++kt) {
        int k0 = kt * 64;
        int cur = kt & 1;
        if (kt + 1 < nkt) STAGE(cur ^ 1, k0 + 64);

        f32x4 sac[4] = {};
        __builtin_amdgcn_s_setprio(1);
        #pragma unroll
        for (int ks = 0; ks < 2; ++ks) {
            #pragma unroll
            for (int ct = 0; ct < 4; ++ct) {
                bf16x8 kfr = *reinterpret_cast<const bf16x8*>(
                    &Ks[cur][(ct * 16 + lr) * 64 + (((ks * 4 + lg) ^ (lr & 7)) * 8)]);
                sac[ct] = __builtin_amdgcn_mfma_f32_16x16x32_bf16(kfr, qf[ks], sac[ct], 0, 0, 0);
            }
        }
        __builtin_amdgcn_s_setprio(0);
        bool maybeMask = (kt >= 2 * qi);
        float sv[4][4];
        float pm = -3.0e38f;
        #pragma unroll
        for (int ct = 0; ct < 4; ++ct) {
            #pragma unroll
            for (int i = 0; i < 4; ++i) {
                float x = sac[ct][i] * 0.125f;
                if (maybeMask) {
                    int kabs = k0 + ct * 16 + lg * 4 + i;
                    if (kabs > qabs) x = -3.0e38f;
                }
                sv[ct][i] = x;
                pm = fmaxf(pm, x);
            }
        }
        pm = fmaxf(pm, __shfl_xor(pm, 16));
        pm = fmaxf(pm, __shfl_xor(pm, 32));

        if (!__all(pm <= m_r + 8.f)) {
            float mn = fmaxf(m_r, pm);
            float alpha = __expf(m_r - mn);
            m_r = mn;
            l_r *= alpha;
            float aC[4];
            #pragma unroll
            for (int i = 0; i < 4; ++i) aC[i] = __shfl(alpha, lg * 4 + i);
            #pragma unroll
            for (int et = 0; et < 4; ++et)
                #pragma unroll
                for (int i = 0; i < 4; ++i) zacc[et][i] *= aC[i];
        }

        float ps = 0.f;
        #pragma unroll
        for (int ct = 0; ct < 4; ++ct) {
            float p0 = __expf(sv[ct][0] - m_r);
            float p1 = __expf(sv[ct][1] - m_r);
            float p2 = __expf(sv[ct][2] - m_r);
            float p3 = __expf(sv[ct][3] - m_r);
            ps += (p0 + p1) + (p2 + p3);
            unsigned int pk0 = cvt_pk_bf16(p0, p1);
            unsigned int pk1 = cvt_pk_bf16(p2, p3);
            *reinterpret_cast<uint2*>(&Pw[lr * PW + ct * 8 + lg * 2]) = make_uint2(pk0, pk1);
        }
        ps += __shfl_xor(ps, 16);
        ps += __shfl_xor(ps, 32);
        l_r += ps;

        __builtin_amdgcn_s_setprio(1);
        #pragma unroll
        for (int ks = 0; ks < 2; ++ks) {
            bf16x8 pa = *reinterpret_cast<const bf16x8*>(&Pw[lr * PW + ks * 16 + lg * 4]);
            #pragma unroll
            for (int et = 0; et < 4; ++et) {
                bf16x8 vf = *reinterpret_cast<const bf16x8*>(
                    &Vs[cur][(et * 16 + lr) * 64 + (((ks * 4 + lg) ^ (lr & 7)) * 8)]);
                zacc[et] = __builtin_amdgcn_mfma_f32_16x16x32_bf16(pa, vf, zacc[et], 0, 0, 0);
            }
        }
        __builtin_amdgcn_s_setprio(0);
        __syncthreads();   // next tile staged everywhere; buf reads done
    }

    float lC[4];
    #pragma unroll
    for (int i = 0; i < 4; ++i) lC[i] = __shfl(l_r, lg * 4 + i);
    #pragma unroll
    for (int et = 0; et < 4; ++et) {
        #pragma unroll
        for (int i = 0; i < 4; ++i) {
            int r = q0 + w * 16 + lg * 4 + i;
            float z = zacc[et][i] / lC[i];
            zb[((size_t)(b_ * SS + r)) * DD + h * DHH + et * 16 + lr] = f2bf(z);
        }
    }
}

// ---------------- output projection (m97 structure): out[8192,768] = zb * wot^T + bo ----------------

__launch_bounds__(256)
__global__ void k_gemm_out(const unsigned short* __restrict__ zb,
                           const unsigned short* __restrict__ wot,
                           const float* __restrict__ bo,
                           float* __restrict__ out) {
    __shared__ unsigned short As[128 * 32];
    __shared__ unsigned short Bs[128 * 32];
    int r0 = blockIdx.x * 128;
    int c0 = blockIdx.y * 128;
    int t = threadIdx.x;
    int w = t >> 6, l = t & 63;
    int lr = l & 15, lg = l >> 4;
    int wr = w >> 1, wc = w & 1;
    int srow = l >> 2, sko = (l & 3) * 8;

    f32x4 acc[4][4] = {};
    for (int k0 = 0; k0 < DD; k0 += 32) {
        __syncthreads();
        #pragma unroll
        for (int c = 0; c < 2; ++c) {
            int seg = w * 2 + c;
            int row = seg * 16 + srow;
            __builtin_amdgcn_global_load_lds(
                (gu32*)(zb + (size_t)(r0 + row) * DD + k0 + sko),
                (lu32*)&As[seg * 512], 16, 0, 0);
            __builtin_amdgcn_global_load_lds(
                (gu32*)(wot + (size_t)(c0 + row) * DD + k0 + sko),
                (lu32*)&Bs[seg * 512], 16, 0, 0);
        }
        __syncthreads();
        bf16x8 af[4], bfr[4];
        #pragma unroll
        for (int m = 0; m < 4; ++m)
            af[m] = *reinterpret_cast<const bf16x8*>(&As[(wr * 64 + m * 16 + lr) * 32 + lg * 8]);
        #pragma unroll
        for (int n = 0; n < 4; ++n)
            bfr[n] = *reinterpret_cast<const bf16x8*>(&Bs[(wc * 64 + n * 16 + lr) * 32 + lg * 8]);
        #pragma unroll
        for (int m = 0; m < 4; ++m)
            #pragma unroll
            for (int n = 0; n < 4; ++n)
                acc[m][n] = __builtin_amdgcn_mfma_f32_16x16x32_bf16(af[m], bfr[n], acc[m][n], 0, 0, 0);
    }
    #pragma unroll
    for (int n = 0; n < 4; ++n) {
        int c = c0 + wc * 64 + n * 16 + lr;
        float bias = bo[c];
        #pragma unroll
        for (int m = 0; m < 4; ++m) {
            #pragma unroll
            for (int i = 0; i < 4; ++i) {
                int r = r0 + wr * 64 + m * 16 + lg * 4 + i;
                out[(size_t)r * DD + c] = acc[m][n][i] + bias;
            }
        }
    }
}

// ---------------- launch ----------------

extern "C" void kernel_launch(void* const* d_in, const int* in_sizes, int n_in,
                              void* d_out, int out_size, void* d_ws, size_t ws_size,
                              hipStream_t stream) {
    const float* x  = (const float*)d_in[0];
    const float* wq = (const float*)d_in[1];
    const float* bq = (const float*)d_in[2];
    const float* wk = (const float*)d_in[3];
    const float* bk = (const float*)d_in[4];
    const float* wv = (const float*)d_in[5];
    const float* bv = (const float*)d_in[6];
    const float* wo = (const float*)d_in[7];
    const float* bo = (const float*)d_in[8];
    float* out = (float*)d_out;

    char* ws = (char*)d_ws;
    size_t off = 0;
    auto alloc = [&](size_t bytes) -> char* {
        char* p = ws + off;
        off += (bytes + 255) & ~(size_t)255;
        return p;
    };
    unsigned short* xb   = (unsigned short*)alloc((size_t)BS * DD * 2);
    unsigned short* wt   = (unsigned short*)alloc((size_t)NQKV * DD * 2);
    unsigned short* wot  = (unsigned short*)alloc((size_t)DD * DD * 2);
    unsigned short* qb   = (unsigned short*)alloc((size_t)BB * HH * SS * DHH * 2);
    unsigned short* kb   = (unsigned short*)alloc((size_t)BB * HH * SS * DHH * 2);
    unsigned short* vtb  = (unsigned short*)alloc((size_t)BB * HH * SS * DHH * 2);
    unsigned short* zb   = (unsigned short*)alloc((size_t)BS * DD * 2);
    (void)ws_size; (void)in_sizes; (void)n_in; (void)out_size;

    k_f32_to_bf16<<<dim3((BS * DD) / (256 * 4)), dim3(256), 0, stream>>>(x, xb, BS * DD);
    k_transpose_wqkv<<<dim3(12, 36), dim3(256), 0, stream>>>(wq, wk, wv, wt);
    k_transpose_wo<<<dim3(12, 12), dim3(256), 0, stream>>>(wo, wot);
    k_gemm_qkv<<<dim3(BS / 128, NQKV / 128), dim3(256), 0, stream>>>(xb, wt, bq, bk, bv, qb, kb, vtb);
    k_attn<<<dim3(768), dim3(512), 0, stream>>>(qb, kb, vtb, zb);
    k_gemm_out<<<dim3(BS / 128, DD / 128), dim3(256), 0, stream>>>(zb, wot, bo, out);
}

// Round 14
// 120.465 us; speedup vs baseline: 1.1123x; 1.1123x over previous
//
#include <hip/hip_runtime.h>
#include <hip/hip_bf16.h>
#include <stdint.h>

#define BB 8
#define SS 1024
#define DD 768
#define HH 12
#define DHH 64
#define BS (BB*SS)        // 8192
#define NQKV (3*HH*DHH)   // 2304

typedef __attribute__((ext_vector_type(8))) short bf16x8;
typedef __attribute__((ext_vector_type(4))) float f32x4;
typedef __attribute__((ext_vector_type(4))) unsigned int u32x4;

typedef const __attribute__((address_space(1))) unsigned int gu32;
typedef __attribute__((address_space(3))) unsigned int lu32;

static __device__ __forceinline__ unsigned short f2bf(float f) {
    union { float f; unsigned int u; } v; v.f = f;
    unsigned int u = v.u;
    unsigned int r = (u + 0x7fffu + ((u >> 16) & 1u)) >> 16;
    return (unsigned short)r;
}

static __device__ __forceinline__ unsigned int cvt_pk_bf16(float lo, float hi) {
    unsigned int r;
    asm("v_cvt_pk_bf16_f32 %0, %1, %2" : "=v"(r) : "v"(lo), "v"(hi));
    return r;
}

// counted-wait barriers for the attn V-pipeline
#define WB2() asm volatile("s_waitcnt vmcnt(2)\ns_barrier" ::: "memory")
#define WB0() asm volatile("s_waitcnt vmcnt(0)\ns_barrier" ::: "memory")

// ---------------- fused prep kernel ----------------
// grid 6720 blocks x 256:
//   [0,6144)    : x f32 -> bf16 cast (4 elems/thread)
//   [6144,6576) : wt[c][d] = W_mat[h][d][e] transpose (64x64 f32 LDS tile)
//   [6576,6720) : wot[d][he] = wo[he][d] transpose

__global__ void k_prep(const float* __restrict__ x,
                       const float* __restrict__ wq, const float* __restrict__ wk,
                       const float* __restrict__ wv, const float* __restrict__ wo,
                       unsigned short* __restrict__ xb,
                       unsigned short* __restrict__ wt,
                       unsigned short* __restrict__ wot) {
    __shared__ float tl[64][65];
    int id = blockIdx.x;
    int t = threadIdx.x;
    if (id < 6144) {
        int i = (id * 256 + t) * 4;
        float4 v = *reinterpret_cast<const float4*>(x + i);
        ushort4 o;
        o.x = f2bf(v.x); o.y = f2bf(v.y); o.z = f2bf(v.z); o.w = f2bf(v.w);
        *reinterpret_cast<ushort4*>(xb + i) = o;
        return;
    }
    int row = t >> 4, c4 = (t & 15) * 4;
    if (id < 6576) {
        int q = id - 6144;            // 0..431
        int rt = q % 12, z = q / 12;  // d-tile, matrix*head
        int mat = z / 12, h = z - mat * 12;
        const float* src = ((mat == 0) ? wq : (mat == 1) ? wk : wv) + (size_t)h * 768 * 64;
        int d0 = rt * 64;
        #pragma unroll
        for (int p = 0; p < 4; ++p) {
            int d = p * 16 + row;
            float4 v = *reinterpret_cast<const float4*>(&src[(size_t)(d0 + d) * 64 + c4]);
            tl[d][c4 + 0] = v.x; tl[d][c4 + 1] = v.y; tl[d][c4 + 2] = v.z; tl[d][c4 + 3] = v.w;
        }
        __syncthreads();
        unsigned short* dstb = wt + ((size_t)(mat * 768 + h * 64)) * 768;
        #pragma unroll
        for (int p = 0; p < 4; ++p) {
            int e = p * 16 + row;
            ushort4 o;
            o.x = f2bf(tl[c4 + 0][e]); o.y = f2bf(tl[c4 + 1][e]);
            o.z = f2bf(tl[c4 + 2][e]); o.w = f2bf(tl[c4 + 3][e]);
            *reinterpret_cast<ushort4*>(&dstb[(size_t)e * 768 + d0 + c4]) = o;
        }
        return;
    }
    {
        int q = id - 6576;            // 0..143
        int r0 = (q % 12) * 64;       // he tile
        int c0 = (q / 12) * 64;       // d tile
        #pragma unroll
        for (int p = 0; p < 4; ++p) {
            int r = p * 16 + row;
            float4 v = *reinterpret_cast<const float4*>(&wo[(size_t)(r0 + r) * 768 + c0 + c4]);
            tl[r][c4 + 0] = v.x; tl[r][c4 + 1] = v.y; tl[r][c4 + 2] = v.z; tl[r][c4 + 3] = v.w;
        }
        __syncthreads();
        #pragma unroll
        for (int p = 0; p < 4; ++p) {
            int c = p * 16 + row;
            ushort4 o;
            o.x = f2bf(tl[c4 + 0][c]); o.y = f2bf(tl[c4 + 1][c]);
            o.z = f2bf(tl[c4 + 2][c]); o.w = f2bf(tl[c4 + 3][c]);
            *reinterpret_cast<ushort4*>(&wot[(size_t)(c0 + c) * 768 + r0 + c4]) = o;
        }
    }
}

// vtb[bh][e][s] = vb[bh][s][e]
__global__ void k_transpose_v(const unsigned short* __restrict__ vb, unsigned short* __restrict__ vtb) {
    __shared__ unsigned short tl[64][68];
    int s0 = blockIdx.x * 64;
    int bh = blockIdx.y;
    const unsigned short* src = vb + (size_t)bh * SS * DHH;
    unsigned short* dst = vtb + (size_t)bh * DHH * SS;
    int t = threadIdx.x;
    #pragma unroll
    for (int i = 0; i < 16; ++i) {
        int idx = t + i * 256;
        int sl = idx >> 6, e = idx & 63;
        tl[sl][e] = src[(size_t)(s0 + sl) * DHH + e];
    }
    __syncthreads();
    #pragma unroll
    for (int i = 0; i < 16; ++i) {
        int idx = t + i * 256;
        int e = idx >> 6, sl = idx & 63;
        dst[(size_t)e * SS + s0 + sl] = tl[sl][e];
    }
}

// ---------------- QKV projection GEMM (m97 structure): C[8192,2304] = xb * wt^T ----------------
// R4-exact (best measured across R5-R12; frozen).

__launch_bounds__(256)
__global__ void k_gemm_qkv(const unsigned short* __restrict__ xb,
                           const unsigned short* __restrict__ wt,
                           const float* __restrict__ bq, const float* __restrict__ bk,
                           const float* __restrict__ bv,
                           unsigned short* __restrict__ qb,
                           unsigned short* __restrict__ kb,
                           unsigned short* __restrict__ vb) {
    __shared__ unsigned short As[128 * 32];
    __shared__ unsigned short Bs[128 * 32];
    int r0 = blockIdx.x * 128;
    int c0 = blockIdx.y * 128;
    int t = threadIdx.x;
    int w = t >> 6, l = t & 63;
    int lr = l & 15, lg = l >> 4;
    int wr = w >> 1, wc = w & 1;
    int srow = l >> 2, sko = (l & 3) * 8;

    f32x4 acc[4][4] = {};
    for (int k0 = 0; k0 < DD; k0 += 32) {
        __syncthreads();
        #pragma unroll
        for (int c = 0; c < 2; ++c) {
            int seg = w * 2 + c;
            int row = seg * 16 + srow;
            __builtin_amdgcn_global_load_lds(
                (gu32*)(xb + (size_t)(r0 + row) * DD + k0 + sko),
                (lu32*)&As[seg * 512], 16, 0, 0);
            __builtin_amdgcn_global_load_lds(
                (gu32*)(wt + (size_t)(c0 + row) * DD + k0 + sko),
                (lu32*)&Bs[seg * 512], 16, 0, 0);
        }
        __syncthreads();
        bf16x8 af[4], bfr[4];
        #pragma unroll
        for (int m = 0; m < 4; ++m)
            af[m] = *reinterpret_cast<const bf16x8*>(&As[(wr * 64 + m * 16 + lr) * 32 + lg * 8]);
        #pragma unroll
        for (int n = 0; n < 4; ++n)
            bfr[n] = *reinterpret_cast<const bf16x8*>(&Bs[(wc * 64 + n * 16 + lr) * 32 + lg * 8]);
        #pragma unroll
        for (int m = 0; m < 4; ++m)
            #pragma unroll
            for (int n = 0; n < 4; ++n)
                acc[m][n] = __builtin_amdgcn_mfma_f32_16x16x32_bf16(af[m], bfr[n], acc[m][n], 0, 0, 0);
    }
    #pragma unroll
    for (int n = 0; n < 4; ++n) {
        int c = c0 + wc * 64 + n * 16 + lr;
        int mat = c / 768;
        int within = c - mat * 768;
        int h = within >> 6, e = within & 63;
        const float* bptr = (mat == 0) ? bq : (mat == 1) ? bk : bv;
        float bias = bptr[within];
        unsigned short* dst = (mat == 0) ? qb : (mat == 1) ? kb : vb;
        #pragma unroll
        for (int m = 0; m < 4; ++m) {
            #pragma unroll
            for (int i = 0; i < 4; ++i) {
                int r = r0 + wr * 64 + m * 16 + lg * 4 + i;
                int b_ = r >> 10, s_ = r & 1023;
                dst[(((size_t)(b_ * HH + h)) * SS + s_) * DHH + e] = f2bf(acc[m][n][i] + bias);
            }
        }
    }
}

// ---------------- flash attention (R11-exact: best passed config) ----------------
// V single-buffered (issued at iter start, consumed after counted-wait WB2),
// K double-buffered; XCD/head-grouped mapping; setprio around MFMA clusters;
// 4 blocks/CU.

#define PW 34   // u32 row stride for P tile

__launch_bounds__(256, 4)
__global__ void k_attn(const unsigned short* __restrict__ qb,
                       const unsigned short* __restrict__ kb,
                       const unsigned short* __restrict__ vtb,
                       unsigned short* __restrict__ zb) {
    __shared__ unsigned short Ks[2][64 * 64];
    __shared__ unsigned short Vs[64 * 64];
    __shared__ unsigned int Pl[4][16 * PW];
    int id = blockIdx.x;           // 0..1535
    int xcd = id & 7;              // round-robin dispatch -> XCD
    int j = id >> 3;               // 0..191 within this XCD
    int bh = xcd * 12 + (j % 12);  // this XCD's 12 heads
    int qi = 15 - (j / 12);        // heavy-first within XCD
    int q0 = qi * 64;

    int t = threadIdx.x, w = t >> 6, l = t & 63;
    int lr = l & 15, lg = l >> 4;
    const unsigned short* Qh = qb + (size_t)bh * SS * DHH;
    const unsigned short* Kh = kb + (size_t)bh * SS * DHH;
    const unsigned short* Vt = vtb + (size_t)bh * DHH * SS;
    int b_ = bh / HH, h = bh - b_ * HH;
    unsigned int* Pw = &Pl[w][0];

    int sr8 = l >> 3;
    int sc = ((l & 7) ^ sr8) * 8;

    auto STAGE_K = [&](int buf, int kbase) {
        #pragma unroll
        for (int c = 0; c < 2; ++c) {
            int seg = w * 2 + c;
            int row = seg * 8 + sr8;
            __builtin_amdgcn_global_load_lds(
                (gu32*)(Kh + (size_t)(kbase + row) * DHH + sc),
                (lu32*)&Ks[buf][seg * 512], 16, 0, 0);
        }
    };
    auto STAGE_V = [&](int kbase) {
        #pragma unroll
        for (int c = 0; c < 2; ++c) {
            int seg = w * 2 + c;
            int row = seg * 8 + sr8;
            __builtin_amdgcn_global_load_lds(
                (gu32*)(Vt + (size_t)row * SS + kbase + sc),
                (lu32*)&Vs[seg * 512], 16, 0, 0);
        }
    };

    int qabs = q0 + w * 16 + lr;
    STAGE_K(0, 0);
    bf16x8 qf[2];
    qf[0] = *reinterpret_cast<const bf16x8*>(Qh + (size_t)qabs * DHH + lg * 8);
    qf[1] = *reinterpret_cast<const bf16x8*>(Qh + (size_t)qabs * DHH + 32 + lg * 8);

    float m_r = -3.0e38f, l_r = 0.f;
    f32x4 zacc[4] = {};
    __syncthreads();   // K(0) ready

    for (int kt = 0; kt <= qi; ++kt) {
        int k0 = kt * 64;
        int cur = kt & 1;
        STAGE_V(k0);                          // V for THIS iter (2 loads, oldest)
        if (kt < qi) STAGE_K(cur ^ 1, k0 + 64);  // K for NEXT iter (2 loads, newest)

        f32x4 sac[4] = {};
        __builtin_amdgcn_s_setprio(1);
        #pragma unroll
        for (int ks = 0; ks < 2; ++ks) {
            #pragma unroll
            for (int ct = 0; ct < 4; ++ct) {
                bf16x8 kfr = *reinterpret_cast<const bf16x8*>(
                    &Ks[cur][(ct * 16 + lr) * 64 + (((ks * 4 + lg) ^ (lr & 7)) * 8)]);
                sac[ct] = __builtin_amdgcn_mfma_f32_16x16x32_bf16(kfr, qf[ks], sac[ct], 0, 0, 0);
            }
        }
        __builtin_amdgcn_s_setprio(0);
        bool diag = (kt == qi);
        float sv[4][4];
        float pm = -3.0e38f;
        #pragma unroll
        for (int ct = 0; ct < 4; ++ct) {
            #pragma unroll
            for (int i = 0; i < 4; ++i) {
                float x = sac[ct][i] * 0.125f;
                if (diag) {
                    int kabs = k0 + ct * 16 + lg * 4 + i;
                    if (kabs > qabs) x = -3.0e38f;
                }
                sv[ct][i] = x;
                pm = fmaxf(pm, x);
            }
        }
        pm = fmaxf(pm, __shfl_xor(pm, 16));
        pm = fmaxf(pm, __shfl_xor(pm, 32));

        if (!__all(pm <= m_r + 8.f)) {
            float mn = fmaxf(m_r, pm);
            float alpha = __expf(m_r - mn);
            m_r = mn;
            l_r *= alpha;
            float aC[4];
            #pragma unroll
            for (int i = 0; i < 4; ++i) aC[i] = __shfl(alpha, lg * 4 + i);
            #pragma unroll
            for (int et = 0; et < 4; ++et)
                #pragma unroll
                for (int i = 0; i < 4; ++i) zacc[et][i] *= aC[i];
        }

        float ps = 0.f;
        #pragma unroll
        for (int ct = 0; ct < 4; ++ct) {
            float p0 = __expf(sv[ct][0] - m_r);
            float p1 = __expf(sv[ct][1] - m_r);
            float p2 = __expf(sv[ct][2] - m_r);
            float p3 = __expf(sv[ct][3] - m_r);
            ps += (p0 + p1) + (p2 + p3);
            unsigned int pk0 = cvt_pk_bf16(p0, p1);
            unsigned int pk1 = cvt_pk_bf16(p2, p3);
            *reinterpret_cast<uint2*>(&Pw[lr * PW + ct * 8 + lg * 2]) = make_uint2(pk0, pk1);
        }
        ps += __shfl_xor(ps, 16);
        ps += __shfl_xor(ps, 32);
        l_r += ps;

        // V(kt) must be fully staged (all waves) before PV; leave K(t+1) in flight.
        if (kt < qi) WB2(); else WB0();

        __builtin_amdgcn_s_setprio(1);
        #pragma unroll
        for (int ks = 0; ks < 2; ++ks) {
            bf16x8 pa = *reinterpret_cast<const bf16x8*>(&Pw[lr * PW + ks * 16 + lg * 4]);
            #pragma unroll
            for (int et = 0; et < 4; ++et) {
                bf16x8 vf = *reinterpret_cast<const bf16x8*>(
                    &Vs[(et * 16 + lr) * 64 + (((ks * 4 + lg) ^ (lr & 7)) * 8)]);
                zacc[et] = __builtin_amdgcn_mfma_f32_16x16x32_bf16(pa, vf, zacc[et], 0, 0, 0);
            }
        }
        __builtin_amdgcn_s_setprio(0);
        __syncthreads();   // drains K(t+1); all Vs reads done before next overwrite
    }

    float lC[4];
    #pragma unroll
    for (int i = 0; i < 4; ++i) lC[i] = __shfl(l_r, lg * 4 + i);
    #pragma unroll
    for (int et = 0; et < 4; ++et) {
        #pragma unroll
        for (int i = 0; i < 4; ++i) {
            int r = q0 + w * 16 + lg * 4 + i;
            float z = zacc[et][i] / lC[i];
            zb[((size_t)(b_ * SS + r)) * DD + h * DHH + et * 16 + lr] = f2bf(z);
        }
    }
}

// ---------------- output projection (m97 structure): out[8192,768] = zb * wot^T + bo ----------------

__launch_bounds__(256)
__global__ void k_gemm_out(const unsigned short* __restrict__ zb,
                           const unsigned short* __restrict__ wot,
                           const float* __restrict__ bo,
                           float* __restrict__ out) {
    __shared__ unsigned short As[128 * 32];
    __shared__ unsigned short Bs[128 * 32];
    int r0 = blockIdx.x * 128;
    int c0 = blockIdx.y * 128;
    int t = threadIdx.x;
    int w = t >> 6, l = t & 63;
    int lr = l & 15, lg = l >> 4;
    int wr = w >> 1, wc = w & 1;
    int srow = l >> 2, sko = (l & 3) * 8;

    f32x4 acc[4][4] = {};
    for (int k0 = 0; k0 < DD; k0 += 32) {
        __syncthreads();
        #pragma unroll
        for (int c = 0; c < 2; ++c) {
            int seg = w * 2 + c;
            int row = seg * 16 + srow;
            __builtin_amdgcn_global_load_lds(
                (gu32*)(zb + (size_t)(r0 + row) * DD + k0 + sko),
                (lu32*)&As[seg * 512], 16, 0, 0);
            __builtin_amdgcn_global_load_lds(
                (gu32*)(wot + (size_t)(c0 + row) * DD + k0 + sko),
                (lu32*)&Bs[seg * 512], 16, 0, 0);
        }
        __syncthreads();
        bf16x8 af[4], bfr[4];
        #pragma unroll
        for (int m = 0; m < 4; ++m)
            af[m] = *reinterpret_cast<const bf16x8*>(&As[(wr * 64 + m * 16 + lr) * 32 + lg * 8]);
        #pragma unroll
        for (int n = 0; n < 4; ++n)
            bfr[n] = *reinterpret_cast<const bf16x8*>(&Bs[(wc * 64 + n * 16 + lr) * 32 + lg * 8]);
        #pragma unroll
        for (int m = 0; m < 4; ++m)
            #pragma unroll
            for (int n = 0; n < 4; ++n)
                acc[m][n] = __builtin_amdgcn_mfma_f32_16x16x32_bf16(af[m], bfr[n], acc[m][n], 0, 0, 0);
    }
    #pragma unroll
    for (int n = 0; n < 4; ++n) {
        int c = c0 + wc * 64 + n * 16 + lr;
        float bias = bo[c];
        #pragma unroll
        for (int m = 0; m < 4; ++m) {
            #pragma unroll
            for (int i = 0; i < 4; ++i) {
                int r = r0 + wr * 64 + m * 16 + lg * 4 + i;
                out[(size_t)r * DD + c] = acc[m][n][i] + bias;
            }
        }
    }
}

// ---------------- launch ----------------

extern "C" void kernel_launch(void* const* d_in, const int* in_sizes, int n_in,
                              void* d_out, int out_size, void* d_ws, size_t ws_size,
                              hipStream_t stream) {
    const float* x  = (const float*)d_in[0];
    const float* wq = (const float*)d_in[1];
    const float* bq = (const float*)d_in[2];
    const float* wk = (const float*)d_in[3];
    const float* bk = (const float*)d_in[4];
    const float* wv = (const float*)d_in[5];
    const float* bv = (const float*)d_in[6];
    const float* wo = (const float*)d_in[7];
    const float* bo = (const float*)d_in[8];
    float* out = (float*)d_out;

    char* ws = (char*)d_ws;
    size_t off = 0;
    auto alloc = [&](size_t bytes) -> char* {
        char* p = ws + off;
        off += (bytes + 255) & ~(size_t)255;
        return p;
    };
    unsigned short* xb   = (unsigned short*)alloc((size_t)BS * DD * 2);
    unsigned short* wt   = (unsigned short*)alloc((size_t)NQKV * DD * 2);
    unsigned short* wot  = (unsigned short*)alloc((size_t)DD * DD * 2);
    unsigned short* qb   = (unsigned short*)alloc((size_t)BB * HH * SS * DHH * 2);
    unsigned short* kb   = (unsigned short*)alloc((size_t)BB * HH * SS * DHH * 2);
    unsigned short* vb   = (unsigned short*)alloc((size_t)BB * HH * SS * DHH * 2);
    unsigned short* vtb  = (unsigned short*)alloc((size_t)BB * HH * SS * DHH * 2);
    unsigned short* zb   = (unsigned short*)alloc((size_t)BS * DD * 2);
    (void)ws_size; (void)in_sizes; (void)n_in; (void)out_size;

    k_prep<<<dim3(6720), dim3(256), 0, stream>>>(x, wq, wk, wv, wo, xb, wt, wot);
    k_gemm_qkv<<<dim3(BS / 128, NQKV / 128), dim3(256), 0, stream>>>(xb, wt, bq, bk, bv, qb, kb, vb);
    k_transpose_v<<<dim3(SS / 64, BB * HH), dim3(256), 0, stream>>>(vb, vtb);
    k_attn<<<dim3(16 * 96), dim3(256), 0, stream>>>(qb, kb, vtb, zb);
    k_gemm_out<<<dim3(BS / 128, DD / 128), dim3(256), 0, stream>>>(zb, wot, bo, out);
}